// Round 9
// baseline (103.866 us; speedup 1.0000x reference)
//
#include <hip/hip_runtime.h>
#include <hip/hip_bf16.h>

typedef __attribute__((ext_vector_type(8))) short short8;
typedef __attribute__((ext_vector_type(4))) float floatx4;

#define NROWS 4096
#define NHALF 2048
#define DDIM  128
#define LDST  136                 // LDS row stride in ushorts (128 + 8 pad -> 272B)
#define SQRT_SCALE 2.6857914f     // sqrt(1/(0.2*ln2)) ; dot of stored z == (sim/T)*log2(e)
#define LN2 0.69314718056f

// ws float layout: [0]=loss acc, [1]=all_num, [2]=k_loss completion counter,
// part [64, 64+4*32*4096) : part[l][k][n] = sum_{m in col-tile k} exp2(z_n . z_m)
//   slot k = column-tile index; for row n (row-tile R=n>>7): k>=R written by block (R,k)
//   row-side, k<R written by block (k,R) col-side -> EXACTLY ONE writer per element,
//   plain stores, no zero-init, no atomics.
#define WS_PART_OFF 64
#define WS_DIAG_OFF 524352        // 64 + 4*32*4096
#define WS_POS_OFF  540736        // + 16384
#define WS_Z_BYTE_OFF 2228480     // (WS_POS_OFF + 16384)*4, 16B aligned

__device__ inline unsigned short f2bf(float f) {
    unsigned u = __builtin_bit_cast(unsigned, f);
    u += 0x7fffu + ((u >> 16) & 1u);          // RNE
    return (unsigned short)(u >> 16);
}

__device__ inline void tilecoords(int idx, int& I, int& J) {
    int j = (int)((sqrtf(8.f * (float)idx + 1.f) - 1.f) * 0.5f);
    while ((j + 1) * (j + 2) / 2 <= idx) ++j; // guard fp rounding
    while (j * (j + 1) / 2 > idx) --j;
    J = j; I = idx - j * (j + 1) / 2;
}

// ---------------- kernel 1: normalize + scale + cast to bf16; zero scalars; all_num --------
__global__ __launch_bounds__(256) void k_norm(const float* __restrict__ emb_i,
                                              const float* __restrict__ emb_j,
                                              const float* __restrict__ jv,
                                              float* __restrict__ wsf,
                                              unsigned short* __restrict__ z) {
    int bx = blockIdx.x, tid = threadIdx.x;
    if (bx == 4096) {                         // all_num = sum(joint_valid)
        __shared__ float sred[256];
        float s = 0.f;
        #pragma unroll
        for (int i = 0; i < 8; ++i) s += jv[tid + 256 * i];
        sred[tid] = s; __syncthreads();
        for (int off = 128; off > 0; off >>= 1) {
            if (tid < off) sred[tid] += sred[tid + off];
            __syncthreads();
        }
        if (tid == 0) wsf[1] = sred[0];
        return;
    }
    if (bx == 0 && tid == 0) { wsf[0] = 0.f; *(unsigned*)&wsf[2] = 0u; }

    int wave = tid >> 6, lane = tid & 63;
    int r = bx * 4 + wave;                    // global row 0..16383
    int l = r >> 12, n = r & 4095;
    const float* src = (n < NHALF) ? (emb_i + ((size_t)l * NHALF + n) * DDIM)
                                   : (emb_j + ((size_t)l * NHALF + (n - NHALF)) * DDIM);
    float2 v = *(const float2*)(src + lane * 2);
    float ss = v.x * v.x + v.y * v.y;
    #pragma unroll
    for (int off = 1; off < 64; off <<= 1) ss += __shfl_xor(ss, off);
    float inv = SQRT_SCALE / fmaxf(sqrtf(ss), 1e-12f);
    unsigned pack = ((unsigned)f2bf(v.y * inv) << 16) | (unsigned)f2bf(v.x * inv);
    *(unsigned*)(z + (size_t)r * DDIM + lane * 2) = pack;
}

// ---------------- kernel 2: PERSISTENT pipelined symmetric sim + exp2 sums -----------------
// R8 post-mortem: container failed twice for R7 AND R8 (different LDS sizes) -> LDS-size
// theory dead; audit found no fault mechanism -> treating as infra flake, resubmitting
// with ONE fix: R8's __launch_bounds__(256,2) empirically caps VGPR at 128 on this
// toolchain (R1 evidence: (256,2) -> VGPR_Count 128 -> spill storm). Live state here is
// ~156 -> R8 would have spilled. Plain __launch_bounds__(256): uncapped (~170-210 VGPR,
// known-safe from R3/R6), 2-3 blocks/CU -> all 512 blocks co-resident, which is all the
// persistent schedule needs.
// Structure: 512 blocks (bx&3 = l -> each XCD pinned to one l, z slice 1MB L2-resident),
// each processes 4-5 upper-tri 128x128 tiles (stride 128 in tile index). Tile k+1's B
// (8 x uint4) and a-fragments are loaded into REGISTERS before computing tile k (L2
// latency hides under ~2000cyc of MFMA+exp2), ds_written to the single 34KB B-buffer
// between the two tile-end barriers. Removes the per-block exposed prologue that R4/R6
// ruled everything else out of (~1000cyc x 2112 blocks / ~512 slots ~ 15us).
// Decision tree: pass -> read counters; third container failure -> revert to R6 shape.
__global__ __launch_bounds__(256) void k_sim(const unsigned short* __restrict__ z,
                                             float* __restrict__ part,
                                             float* __restrict__ diag,
                                             float* __restrict__ pos) {
    __shared__ __align__(16) unsigned short lds[128 * LDST];
    __shared__ float cred[4][128];
    int bx = blockIdx.x, tid = threadIdx.x;
    int l = bx & 3, ppos = bx >> 2;           // ppos in [0,128)
    int nt = 4 + (ppos < 16);                 // 16*5 + 112*4 = 528 tiles per l
    int wave = tid >> 6, lane = tid & 63, m = lane & 15, quad = lane >> 4;
    const unsigned short* zl = z + (size_t)l * NROWS * DDIM;
    int l4 = l * NROWS;

    int I, J;
    tilecoords(ppos, I, J);

    // prologue: a-fragments + stage B for tile 0
    short8 a[2][4];
    #pragma unroll
    for (int rs = 0; rs < 2; ++rs) {
        const unsigned short* pa = zl + (size_t)(I * 128 + wave * 32 + rs * 16 + m) * DDIM + quad * 8;
        #pragma unroll
        for (int kk = 0; kk < 4; ++kk) a[rs][kk] = *(const short8*)(pa + kk * 32);
    }
    #pragma unroll
    for (int i = 0; i < 8; ++i) {
        int chunk = tid + 256 * i;
        int col = chunk >> 4, off = chunk & 15;
        uint4 d = *(const uint4*)(zl + (size_t)(J * 128 + col) * DDIM + off * 8);
        *(uint4*)&lds[col * LDST + off * 8] = d;
    }
    __syncthreads();

    for (int k = 0; k < nt; ++k) {
        // ---- issue next tile's prefetch FIRST (latency hides under compute below) ----
        int nidx = ppos + (k + 1) * 128;
        if (nidx >= 528) nidx = ppos;         // clamped dummy on last iter (harmless reload)
        int In, Jn;
        tilecoords(nidx, In, Jn);
        uint4 pf[8];
        #pragma unroll
        for (int i = 0; i < 8; ++i) {
            int chunk = tid + 256 * i;
            int col = chunk >> 4, off = chunk & 15;
            pf[i] = *(const uint4*)(zl + (size_t)(Jn * 128 + col) * DDIM + off * 8);
        }
        short8 an[2][4];
        #pragma unroll
        for (int rs = 0; rs < 2; ++rs) {
            const unsigned short* pa = zl + (size_t)(In * 128 + wave * 32 + rs * 16 + m) * DDIM + quad * 8;
            #pragma unroll
            for (int kk = 0; kk < 4; ++kk) an[rs][kk] = *(const short8*)(pa + kk * 32);
        }

        // ---- compute current tile from lds ----
        int wr0 = I * 128 + wave * 32, cg0 = J * 128;
        floatx4 rsum[2];
        rsum[0] = (floatx4){0.f, 0.f, 0.f, 0.f};
        rsum[1] = (floatx4){0.f, 0.f, 0.f, 0.f};
        float csum[8];
        #pragma unroll
        for (int g = 0; g < 8; ++g) csum[g] = 0.f;

        #pragma unroll
        for (int cs = 0; cs < 8; ++cs) {      // 16-col subtiles
            int ct = cg0 + cs * 16;           // tile column base (wave-uniform)
            const unsigned short* lp = &lds[(cs * 16 + m) * LDST + quad * 8];
            short8 b0 = *(const short8*)(lp);
            short8 b1 = *(const short8*)(lp + 32);
            short8 b2 = *(const short8*)(lp + 64);
            short8 b3 = *(const short8*)(lp + 96);
            #pragma unroll
            for (int rs = 0; rs < 2; ++rs) {
                floatx4 acc = (floatx4){0.f, 0.f, 0.f, 0.f};
                acc = __builtin_amdgcn_mfma_f32_16x16x32_bf16(a[rs][0], b0, acc, 0, 0, 0);
                acc = __builtin_amdgcn_mfma_f32_16x16x32_bf16(a[rs][1], b1, acc, 0, 0, 0);
                acc = __builtin_amdgcn_mfma_f32_16x16x32_bf16(a[rs][2], b2, acc, 0, 0, 0);
                acc = __builtin_amdgcn_mfma_f32_16x16x32_bf16(a[rs][3], b3, acc, 0, 0, 0);
                int rowbase = wr0 + rs * 16;
                bool isdiag = (ct == rowbase);          // only when I==J
                bool ispos  = (ct == rowbase + 2048);   // only when J==I+16
                if (isdiag || ispos) {        // rare, wave-uniform branch
                    int c = m - (quad << 2);  // acc[c] holds sim[rowbase+quad*4+c][ct+m]
                    if (c >= 0 && c < 4) {    // -> diagonal element iff quad*4+c == m
                        float v = acc[c];
                        if (isdiag) diag[l4 + rowbase + m] = v;
                        else {                // sim[r, r+2048]; pos symmetric across halves
                            pos[l4 + rowbase + m] = v;
                            pos[l4 + rowbase + m + NHALF] = v;
                        }
                    }
                }
                float t = 0.f;
                #pragma unroll
                for (int c = 0; c < 4; ++c) {
                    float e = __builtin_amdgcn_exp2f(acc[c]);
                    rsum[rs][c] += e;
                    t += e;
                }
                csum[cs] += t;
            }
        }
        // row side: reduce across the 16 column-lanes; plain stores to slot J
        #pragma unroll
        for (int off = 1; off < 16; off <<= 1)
            #pragma unroll
            for (int rs = 0; rs < 2; ++rs)
                #pragma unroll
                for (int c = 0; c < 4; ++c)
                    rsum[rs][c] += __shfl_xor(rsum[rs][c], off);
        float* plJ = part + (size_t)(l * 32 + J) * 4096;
        if (m == 0) {                         // lanes 0,16,32,48
            #pragma unroll
            for (int rs = 0; rs < 2; ++rs)
                #pragma unroll
                for (int c = 0; c < 4; ++c)
                    plJ[wr0 + rs * 16 + quad * 4 + c] = rsum[rs][c];
        }
        // col side partials into cred
        if (I != J) {
            #pragma unroll
            for (int g = 0; g < 8; ++g) {     // finish reduce over the 16 rows (bits 4,5)
                float v = csum[g];
                v += __shfl_xor(v, 16);
                v += __shfl_xor(v, 32);
                if (quad == 0) cred[wave][g * 16 + m] = v;
            }
        }
        __syncthreads();                      // all LDS reads done, cred complete
        // col-side store (unique writer, slot I) + overwrite B-buffer with prefetched tile
        if (I != J && tid < 128) {
            float s = cred[0][tid] + cred[1][tid] + cred[2][tid] + cred[3][tid];
            part[(size_t)(l * 32 + I) * 4096 + cg0 + tid] = s;
        }
        #pragma unroll
        for (int i = 0; i < 8; ++i) {
            int chunk = tid + 256 * i;
            int col = chunk >> 4, off = chunk & 15;
            *(uint4*)&lds[col * LDST + off * 8] = pf[i];
        }
        __syncthreads();                      // B ready; cred consumed (safe to rewrite)
        // advance pipeline
        #pragma unroll
        for (int rs = 0; rs < 2; ++rs)
            #pragma unroll
            for (int kk = 0; kk < 4; ++kk) a[rs][kk] = an[rs][kk];
        I = In; J = Jn;
    }
}

// ---------------- kernel 3: gather 32 partials/row -> loss; last block finalizes -----------
__global__ __launch_bounds__(256) void k_loss(const float* __restrict__ jv,
                                              const float* __restrict__ part,
                                              const float* __restrict__ diag,
                                              const float* __restrict__ pos,
                                              float* __restrict__ wsf,
                                              float* __restrict__ out) {
    __shared__ float sred[256];
    int tid = threadIdx.x;
    int r = blockIdx.x * 256 + tid;           // 64 blocks x 256 = 16384 rows
    int l = r >> 12, n = r & 4095;
    const float* pl = part + (size_t)l * 32 * 4096 + n;
    float s = 0.f;
    #pragma unroll
    for (int k = 0; k < 32; ++k) s += pl[(size_t)k * 4096];   // coalesced across lanes
    float denom = s - __builtin_amdgcn_exp2f(diag[r]);
    float contrib = LN2 * (__builtin_amdgcn_logf(denom) - pos[r]); // logf = v_log_f32 = log2
    float local = contrib * jv[n & (NHALF - 1)];
    sred[tid] = local; __syncthreads();
    for (int off = 128; off > 0; off >>= 1) {
        if (tid < off) sred[tid] += sred[tid + off];
        __syncthreads();
    }
    if (tid == 0) {
        atomicAdd(&wsf[0], sred[0]);
        __threadfence();                      // order loss-add before counter-add
        unsigned c = atomicAdd((unsigned*)&wsf[2], 1u);
        if (c == 63) {                        // 64th (last) block: finalize
            float tot = atomicAdd(&wsf[0], 0.f);   // device-scope coherent read
            out[0] = tot / (2.f * wsf[1]);
        }
    }
}

extern "C" void kernel_launch(void* const* d_in, const int* in_sizes, int n_in,
                              void* d_out, int out_size, void* d_ws, size_t ws_size,
                              hipStream_t stream) {
    const float* emb_i = (const float*)d_in[0];
    const float* emb_j = (const float*)d_in[1];
    const float* jv    = (const float*)d_in[2];
    float* wsf  = (float*)d_ws;
    float* part = wsf + WS_PART_OFF;
    float* diag = wsf + WS_DIAG_OFF;
    float* pos  = wsf + WS_POS_OFF;
    unsigned short* z = (unsigned short*)((char*)d_ws + WS_Z_BYTE_OFF);
    float* out = (float*)d_out;

    k_norm <<<4097, 256, 0, stream>>>(emb_i, emb_j, jv, wsf, z);
    k_sim  <<<512,  256, 0, stream>>>(z, part, diag, pos);   // persistent, 4-5 tiles/block
    k_loss <<<64,   256, 0, stream>>>(jv, part, diag, pos, wsf, out);
}